// Round 7
// baseline (1161.325 us; speedup 1.0000x reference)
//
#include <hip/hip_runtime.h>
#include <hip/hip_cooperative_groups.h>

namespace cg = cooperative_groups;

#define Nn 50000
#define Ee 800000
#define Gg 1000
#define Hh 128
#define Cc 6
#define EPSf 1e-5f
#define SB 1024                       // elements per scan block
#define NSB ((Nn + SB - 1) / SB)      // 49
#define NBH 64                        // histogram blocks
#define EPB (Ee / NBH)                // 12500 edges per histogram block
#define NW (Nn / 2)                   // 25000 packed u16-pair words
#define HWH (NW / 2)                  // 12500 words per half-pass (50 KB LDS)
#define LGRID 768                     // cooperative layer-loop grid (3 blocks/CU)

typedef unsigned short u16;
typedef unsigned int u32;
typedef __attribute__((ext_vector_type(8))) short bf16x8;
typedef __attribute__((ext_vector_type(4))) float f32x4;
typedef __attribute__((ext_vector_type(4))) unsigned int u32x4;  // native vec for nontemporal store

static __device__ inline u16 f2bf(float f) {
    u32 u = __float_as_uint(f);
    u32 r = (u + 0x7fffu + ((u >> 16) & 1u)) >> 16;   // RNE
    return (u16)r;
}
static __device__ inline float bf_lo(u32 v) { return __uint_as_float(v << 16); }
static __device__ inline float bf_hi(u32 v) { return __uint_as_float(v & 0xffff0000u); }
static __device__ inline u32 pack2(float a, float b) {
    return ((u32)f2bf(b) << 16) | (u32)f2bf(a);
}

// ---------------- prologue A: zero stats, W->bf16 W^T (3 blocks) ----------------
__global__ __launch_bounds__(256) void k_pre(const float* __restrict__ W3,
                                             u16* __restrict__ WT3,
                                             float* __restrict__ stats3) {
    int t = blockIdx.x * blockDim.x + threadIdx.x;
    if (t < 3 * 2 * Hh) stats3[t] = 0.0f;

    __shared__ u16 tbuf[Hh * 136];
    int l = blockIdx.x;                // 3 blocks, one per layer
    const float* W = W3 + l * Hh * Hh;
    u16* WT = WT3 + l * Hh * Hh;
    int tid = threadIdx.x;
#pragma unroll
    for (int i = 0; i < 16; i++) {
        int v = tid + 256 * i;         // float4 idx over 4096
        int r = v >> 5, c4 = v & 31;
        float4 d = ((const float4*)W)[v];
        u16* p = tbuf + r * 136 + c4 * 4;
        p[0] = f2bf(d.x); p[1] = f2bf(d.y); p[2] = f2bf(d.z); p[3] = f2bf(d.w);
    }
    __syncthreads();
#pragma unroll
    for (int i = 0; i < 64; i++) {
        int o = tid + 256 * i;         // u16 idx over 16384
        int n = o >> 7, k = o & 127;
        WT[o] = tbuf[k * 136 + n];
    }
}

// ---------------- LDS-privatized in-degree histogram: ZERO global atomics ----------------
__global__ __launch_bounds__(1024) void k_hist(const int* __restrict__ ei_dst,
                                               u16* __restrict__ rankL,
                                               u32* __restrict__ partials) {
    __shared__ u32 h[HWH];            // 50 KB
    int b = blockIdx.x, t = threadIdx.x;
    int e0 = b * EPB;
    u32* P = partials + b * NW;
#pragma unroll 1
    for (int half = 0; half < 2; half++) {
        int wlo = half * HWH;
        for (int i = t; i < HWH; i += 1024) h[i] = 0u;
        __syncthreads();
        for (int i = t; i < EPB; i += 1024) {
            int d = ei_dst[e0 + i];
            int w = d >> 1;
            if (w >= wlo && w < wlo + HWH) {
                u32 old = atomicAdd(&h[w - wlo], (d & 1) ? 65536u : 1u);
                rankL[e0 + i] = (u16)((d & 1) ? (old >> 16) : (old & 0xffffu));
            }
        }
        __syncthreads();
        for (int i = t; i < HWH; i += 1024) P[wlo + i] = h[i];
        __syncthreads();
    }
}

// ---------------- scan phase 1 (now fused with partials merge) + dis + gstart ----------------
// Merges the 64 per-block partial histograms in-register (writing base_off),
// derives indeg without a global indeg buffer, then does the block scan.
__global__ __launch_bounds__(256) void k_scan1(const u32* __restrict__ partials,
                                               u32* __restrict__ base_off,
                                               int* __restrict__ rs,
                                               int* __restrict__ bsum,
                                               float* __restrict__ dis,
                                               const int* __restrict__ batch,
                                               int* __restrict__ gstart) {
    __shared__ int ts[256];
    int b = blockIdx.x;
    int t = threadIdx.x;
    int base = b * SB + t * 4;        // 4 nodes = 2 packed words
    int v[4] = {0, 0, 0, 0};
    if (base < Nn) {                  // Nn%4==0 so whole quad in-bounds
        int w0 = base >> 1;
        u32 run0 = 0, run1 = 0;
#pragma unroll 8
        for (int b2 = 0; b2 < NBH; b2++) {
            u32 p0 = partials[b2 * NW + w0];
            u32 p1 = partials[b2 * NW + w0 + 1];
            base_off[b2 * NW + w0] = run0;
            base_off[b2 * NW + w0 + 1] = run1;
            run0 += p0; run1 += p1;
        }
        v[0] = (int)(run0 & 0xffffu); v[1] = (int)(run0 >> 16);
        v[2] = (int)(run1 & 0xffffu); v[3] = (int)(run1 >> 16);
        dis[base]     = rsqrtf((float)v[0] + 1.0f);
        dis[base + 1] = rsqrtf((float)v[1] + 1.0f);
        dis[base + 2] = rsqrtf((float)v[2] + 1.0f);
        dis[base + 3] = rsqrtf((float)v[3] + 1.0f);
    }
    int g = b * 256 + t;
    if (g <= Gg) {
        int lo = 0, hi = Nn;
        while (lo < hi) {
            int mid = (lo + hi) >> 1;
            if (batch[mid] < g) lo = mid + 1; else hi = mid;
        }
        gstart[g] = lo;
    }
    int tsum = v[0] + v[1] + v[2] + v[3];
    ts[t] = tsum;
    __syncthreads();
    for (int off = 1; off < 256; off <<= 1) {
        int x = (t >= off) ? ts[t - off] : 0;
        __syncthreads();
        ts[t] += x;
        __syncthreads();
    }
    int run = (t == 0) ? 0 : ts[t - 1];
    if (t == 255) bsum[b] = ts[255];
#pragma unroll
    for (int j = 0; j < 4; j++) {
        int i = base + j;
        if (i < Nn) { rs[i] = run; run += v[j]; }
    }
}

// ---------------- scan phase 2: per-block redundant top-scan + add ----------------
__global__ __launch_bounds__(256) void k_scan2(int* __restrict__ rs,
                                               const int* __restrict__ bsum) {
    __shared__ int lboff[NSB];
    int t = threadIdx.x;
    if (t < 64) {
        int orig = (t < NSB) ? bsum[t] : 0;
        int v = orig;
#pragma unroll
        for (int off = 1; off < 64; off <<= 1) {
            int u = __shfl_up(v, off, 64);
            if (t >= off) v += u;
        }
        if (t < NSB) lboff[t] = v - orig;   // exclusive
    }
    __syncthreads();
    int i = blockIdx.x * blockDim.x + t;
    if (i < Nn) rs[i] += lboff[i >> 10];
    if (blockIdx.x == 0 && t == 0) rs[Nn] = Ee;
}

// ---------------- counting-sort fill: 4B packed {w:bf16 | src:u16}, ATOMIC-FREE ----------------
__global__ void k_fill(const int* __restrict__ ei, const int* __restrict__ rs,
                       const u16* __restrict__ rankL,
                       const u32* __restrict__ base_off,
                       const float* __restrict__ dis, u32* __restrict__ recs) {
    int e = blockIdx.x * blockDim.x + threadIdx.x;
    if (e >= Ee) return;
    int s = ei[e];
    int d = ei[Ee + e];
    int blk = e / EPB;
    u32 bo = base_off[blk * NW + (d >> 1)];
    int rank = (int)rankL[e] + (int)((d & 1) ? (bo >> 16) : (bo & 0xffffu));
    int slot = rs[d] + rank;
    float w = dis[s] * dis[d];
    recs[slot] = ((u32)f2bf(w) << 16) | (u32)s;   // s < 50000 < 65536
}

// ================= device bodies shared by megakernel and fallback =================

// gather one node (one wave). Wave-uniform node; lanes: lg=lane>>4 edge slot,
// lc=lane&15 uint4 column. 4 edges per dwordx4 load.
static __device__ inline void gather_node(int node, int lane, int lg, int lc,
                                          const uint4* __restrict__ rows4,
                                          const float* __restrict__ dis,
                                          const float* __restrict__ bias,
                                          const int* __restrict__ rs,
                                          const u32* __restrict__ recs,
                                          u16* __restrict__ Ah) {
    float acc[8] = {0.f, 0.f, 0.f, 0.f, 0.f, 0.f, 0.f, 0.f};
    int beg = rs[node];
    int end = rs[node + 1];
    for (int base = beg; base < end; base += 64) {
        int me = base + lane;
        u32 myrec = recs[me < end ? me : end - 1];
        int cnt = end - base;
        if (cnt > 64) cnt = 64;
        for (int i0 = 0; i0 < cnt; i0 += 16) {
            u32 rr[4]; float ww[4]; uint4 vv[4];
#pragma unroll
            for (int j = 0; j < 4; j++) {
                int si = i0 + j * 4 + lg;
                int sc = si < cnt ? si : cnt - 1;
                u32 rec = __shfl(myrec, sc, 64);
                rr[j] = rec & 0xffffu;
                ww[j] = (si < cnt) ? __uint_as_float(rec & 0xffff0000u) : 0.0f;
            }
#pragma unroll
            for (int j = 0; j < 4; j++) vv[j] = rows4[rr[j] * 16 + lc];
#pragma unroll
            for (int j = 0; j < 4; j++) {
                acc[0] += bf_lo(vv[j].x) * ww[j];
                acc[1] += bf_hi(vv[j].x) * ww[j];
                acc[2] += bf_lo(vv[j].y) * ww[j];
                acc[3] += bf_hi(vv[j].y) * ww[j];
                acc[4] += bf_lo(vv[j].z) * ww[j];
                acc[5] += bf_hi(vv[j].z) * ww[j];
                acc[6] += bf_lo(vv[j].w) * ww[j];
                acc[7] += bf_hi(vv[j].w) * ww[j];
            }
        }
    }
#pragma unroll
    for (int k = 0; k < 8; k++) {
        acc[k] += __shfl_xor(acc[k], 16, 64);
        acc[k] += __shfl_xor(acc[k], 32, 64);
    }
    if (lg == 0) {
        float sn = dis[node];
        sn = sn * sn;
        uint4 hv = rows4[node * 16 + lc];
        const float4* bq = (const float4*)bias;
        float4 b0 = bq[lc * 2];
        float4 b1 = bq[lc * 2 + 1];
        acc[0] = acc[0] + bf_lo(hv.x) * sn + b0.x;
        acc[1] = acc[1] + bf_hi(hv.x) * sn + b0.y;
        acc[2] = acc[2] + bf_lo(hv.y) * sn + b0.z;
        acc[3] = acc[3] + bf_hi(hv.y) * sn + b0.w;
        acc[4] = acc[4] + bf_lo(hv.z) * sn + b1.x;
        acc[5] = acc[5] + bf_hi(hv.z) * sn + b1.y;
        acc[6] = acc[6] + bf_lo(hv.w) * sn + b1.z;
        acc[7] = acc[7] + bf_hi(hv.w) * sn + b1.w;
        u32x4 o;
        o.x = pack2(acc[0], acc[1]);
        o.y = pack2(acc[2], acc[3]);
        o.z = pack2(acc[4], acc[5]);
        o.w = pack2(acc[6], acc[7]);
        __builtin_nontemporal_store(o, (u32x4*)Ah + node * 16 + lc);
    }
}

// one GEMM tile (64 rows), mode-1 (fused BN-normalize+ReLU on A from LDS scale/shift)
static __device__ inline void gemm_tile_m1(int tile, int tid,
                                           const u16* __restrict__ Xin,
                                           const u16* __restrict__ wt,
                                           const float* __restrict__ s_scale,
                                           const float* __restrict__ s_shift,
                                           u16* __restrict__ Yh) {
    int wv = tid >> 6, lane = tid & 63;
    int m = lane & 15, q = lane >> 4;
    int row0 = tile * 64 + wv * 16;
    int lrow = row0 + m;
    if (lrow >= Nn) lrow = Nn - 1;
    const u16* xrow = Xin + lrow * Hh + q * 8;

    f32x4 acc[8] = {};
#pragma unroll
    for (int k0 = 0; k0 < Hh; k0 += 32) {
        int cb = k0 + q * 8;
        uint4 p = *(const uint4*)(xrow + k0);
        float4 sc0 = *(const float4*)(s_scale + cb);
        float4 sc1 = *(const float4*)(s_scale + cb + 4);
        float4 sh0 = *(const float4*)(s_shift + cb);
        float4 sh1 = *(const float4*)(s_shift + cb + 4);
        float f0 = fmaxf(bf_lo(p.x) * sc0.x + sh0.x, 0.0f);
        float f1 = fmaxf(bf_hi(p.x) * sc0.y + sh0.y, 0.0f);
        float f2 = fmaxf(bf_lo(p.y) * sc0.z + sh0.z, 0.0f);
        float f3 = fmaxf(bf_hi(p.y) * sc0.w + sh0.w, 0.0f);
        float f4 = fmaxf(bf_lo(p.z) * sc1.x + sh1.x, 0.0f);
        float f5 = fmaxf(bf_hi(p.z) * sc1.y + sh1.y, 0.0f);
        float f6 = fmaxf(bf_lo(p.w) * sc1.z + sh1.z, 0.0f);
        float f7 = fmaxf(bf_hi(p.w) * sc1.w + sh1.w, 0.0f);
        union { bf16x8 v; u32 u[4]; } cv;
        cv.u[0] = pack2(f0, f1);
        cv.u[1] = pack2(f2, f3);
        cv.u[2] = pack2(f4, f5);
        cv.u[3] = pack2(f6, f7);
        bf16x8 a = cv.v;
#pragma unroll
        for (int t = 0; t < 8; t++) {
            bf16x8 bb = *(const bf16x8*)(wt + (t * 16 + m) * 136 + k0 + q * 8);
            acc[t] = __builtin_amdgcn_mfma_f32_16x16x32_bf16(a, bb, acc[t], 0, 0, 0);
        }
    }
    int orow0 = row0 + q * 4;
#pragma unroll
    for (int t = 0; t < 8; t++) {
#pragma unroll
        for (int r = 0; r < 4; r++) {
            int rr = orow0 + r;
            if (rr < Nn) Yh[rr * Hh + t * 16 + m] = f2bf(acc[t][r]);
        }
    }
}

// ================= cooperative megakernel: the whole 3-layer loop =================
// Phases (gather -> stats -> gemm) separated by grid.sync(); replaces 8 launches.
__global__ __launch_bounds__(256, 3) void k_layers(u16* __restrict__ Yh,
                                                   u16* __restrict__ Ah,
                                                   const float* __restrict__ dis,
                                                   const float* __restrict__ conv_b3,
                                                   const int* __restrict__ rs,
                                                   const u32* __restrict__ recs,
                                                   float* __restrict__ stats3,
                                                   const float* __restrict__ bn_g,
                                                   const float* __restrict__ bn_b,
                                                   const u16* __restrict__ WT3) {
    cg::grid_group grid = cg::this_grid();
    __shared__ __align__(16) unsigned char smem[Hh * 136 * 2 + 2 * Hh * 4];  // 35840 B
    int tid = threadIdx.x;
    int lane = tid & 63, lg = lane >> 4, lc = lane & 15;

    for (int l = 0; l < 3; l++) {
        // ---- phase A: CSR gather (Yh -> Ah), grid-stride over node quads ----
        {
            const float* bias = conv_b3 + l * Hh;
            const uint4* rows4 = (const uint4*)Yh;
            for (int qd = blockIdx.x; qd < Nn / 4; qd += gridDim.x) {
                int node = qd * 4 + (tid >> 6);          // wave-uniform
                gather_node(node, lane, lg, lc, rows4, dis, bias, rs, recs, Ah);
            }
        }
        grid.sync();
        // ---- phase B: BN stats (Ah -> stats3[l]), grid-stride ----
        {
            float* stats = stats3 + l * 2 * Hh;
            float (*sh)[256] = (float (*)[256])smem;     // 4 KB
            int jc = tid & 63, ro = tid >> 6;
            const u32* col = (const u32*)Ah + jc;
            float sx = 0.f, sy = 0.f, qx = 0.f, qy = 0.f;
            for (int r = blockIdx.x * 16 + ro * 4; r < Nn; r += gridDim.x * 16) {
                u32 v[4];
#pragma unroll
                for (int k = 0; k < 4; k++) {
                    int rr = r + k;
                    v[k] = (rr < Nn) ? col[rr * 64] : 0u;
                }
#pragma unroll
                for (int k = 0; k < 4; k++) {
                    float a = bf_lo(v[k]), b = bf_hi(v[k]);
                    sx += a; sy += b; qx += a * a; qy += b * b;
                }
            }
            sh[0][tid] = sx; sh[1][tid] = sy; sh[2][tid] = qx; sh[3][tid] = qy;
            __syncthreads();
            if (tid < 64) {
                sx = sh[0][tid] + sh[0][tid + 64] + sh[0][tid + 128] + sh[0][tid + 192];
                sy = sh[1][tid] + sh[1][tid + 64] + sh[1][tid + 128] + sh[1][tid + 192];
                qx = sh[2][tid] + sh[2][tid + 64] + sh[2][tid + 128] + sh[2][tid + 192];
                qy = sh[3][tid] + sh[3][tid + 64] + sh[3][tid + 128] + sh[3][tid + 192];
                atomicAdd(&stats[2 * tid], sx);
                atomicAdd(&stats[2 * tid + 1], sy);
                atomicAdd(&stats[Hh + 2 * tid], qx);
                atomicAdd(&stats[Hh + 2 * tid + 1], qy);
            }
        }
        grid.sync();
        // ---- phase C: next-layer GEMM with fused BN (Ah -> Yh), layers 1,2 ----
        if (l < 2) {
            const u16* WT = WT3 + (l + 1) * Hh * Hh;
            const float* stats = stats3 + l * 2 * Hh;
            const float* gam = bn_g + l * Hh;
            const float* bet = bn_b + l * Hh;
            u16* wt = (u16*)smem;                                  // 34816 B
            float* s_scale = (float*)(smem + Hh * 136 * 2);        // 512 B
            float* s_shift = s_scale + Hh;                         // 512 B
            if (tid < Hh) {
                float mu = stats[tid] * (1.0f / Nn);
                float var = stats[Hh + tid] * (1.0f / Nn) - mu * mu;
                float sc = rsqrtf(var + EPSf) * gam[tid];
                s_scale[tid] = sc;
                s_shift[tid] = bet[tid] - mu * sc;
            }
#pragma unroll
            for (int i = 0; i < 8; i++) {
                int v = tid + 256 * i;
                int n = v >> 4, k8 = v & 15;
                uint4 d = ((const uint4*)WT)[v];
                *((uint4*)(wt + n * 136 + k8 * 8)) = d;
            }
            __syncthreads();
            for (int tile = blockIdx.x; tile < (Nn + 63) / 64; tile += gridDim.x)
                gemm_tile_m1(tile, tid, Ah, wt, s_scale, s_shift, Yh);
            grid.sync();
        }
    }
}

// ================= standalone fallback kernels (if coop launch unavailable) =================
__global__ __launch_bounds__(256) void k_gather(const u16* __restrict__ Yh,
                                                const float* __restrict__ dis,
                                                const float* __restrict__ bias,
                                                const int* __restrict__ rs,
                                                const u32* __restrict__ recs,
                                                u16* __restrict__ Ah) {
    int node = blockIdx.x * 4 + (threadIdx.x >> 6);
    if (node >= Nn) return;
    int lane = threadIdx.x & 63;
    gather_node(node, lane, lane >> 4, lane & 15, (const uint4*)Yh, dis, bias, rs, recs, Ah);
}

__global__ __launch_bounds__(256) void k_stats(const u16* __restrict__ Ah,
                                               float* __restrict__ stats) {
    __shared__ float sh[4][256];
    int t = threadIdx.x;
    int jc = t & 63, ro = t >> 6;
    const u32* col = (const u32*)Ah + jc;
    float sx = 0.f, sy = 0.f, qx = 0.f, qy = 0.f;
    for (int r = blockIdx.x * 16 + ro * 4; r < Nn; r += 4096) {
        u32 v[4];
#pragma unroll
        for (int k = 0; k < 4; k++) {
            int rr = r + k;
            v[k] = (rr < Nn) ? col[rr * 64] : 0u;
        }
#pragma unroll
        for (int k = 0; k < 4; k++) {
            float a = bf_lo(v[k]), b = bf_hi(v[k]);
            sx += a; sy += b; qx += a * a; qy += b * b;
        }
    }
    sh[0][t] = sx; sh[1][t] = sy; sh[2][t] = qx; sh[3][t] = qy;
    __syncthreads();
    if (t < 64) {
        sx = sh[0][t] + sh[0][t + 64] + sh[0][t + 128] + sh[0][t + 192];
        sy = sh[1][t] + sh[1][t + 64] + sh[1][t + 128] + sh[1][t + 192];
        qx = sh[2][t] + sh[2][t + 64] + sh[2][t + 128] + sh[2][t + 192];
        qy = sh[3][t] + sh[3][t + 64] + sh[3][t + 128] + sh[3][t + 192];
        atomicAdd(&stats[2 * t], sx);
        atomicAdd(&stats[2 * t + 1], sy);
        atomicAdd(&stats[Hh + 2 * t], qx);
        atomicAdd(&stats[Hh + 2 * t + 1], qy);
    }
}

// mode 1: fused BN on bf16 A (fallback)   mode 2: f32 A + in-reg cast (layer 0)
__global__ __launch_bounds__(256) void k_gemm(const u16* __restrict__ Xin,
                                              const float* __restrict__ Xf,
                                              const u16* __restrict__ WT,
                                              u16* __restrict__ Yh,
                                              const float* __restrict__ stats,
                                              const float* __restrict__ gam,
                                              const float* __restrict__ bet,
                                              int mode) {
    __shared__ u16 wt[Hh * 136];
    __shared__ float s_scale[Hh], s_shift[Hh];
    int tid = threadIdx.x;

    if (mode == 1 && tid < Hh) {
        float mu = stats[tid] * (1.0f / Nn);
        float var = stats[Hh + tid] * (1.0f / Nn) - mu * mu;
        float sc = rsqrtf(var + EPSf) * gam[tid];
        s_scale[tid] = sc;
        s_shift[tid] = bet[tid] - mu * sc;
    }
#pragma unroll
    for (int i = 0; i < 8; i++) {
        int v = tid + 256 * i;
        int n = v >> 4, k8 = v & 15;
        uint4 d = ((const uint4*)WT)[v];
        *((uint4*)(wt + n * 136 + k8 * 8)) = d;
    }
    __syncthreads();

    if (mode == 1) {
        gemm_tile_m1(blockIdx.x, tid, Xin, wt, s_scale, s_shift, Yh);
        return;
    }

    int wv = tid >> 6, lane = tid & 63;
    int m = lane & 15, q = lane >> 4;
    int row0 = blockIdx.x * 64 + wv * 16;
    int lrow = row0 + m;
    if (lrow >= Nn) lrow = Nn - 1;
    const float* xfrow = Xf + lrow * Hh + q * 8;

    f32x4 acc[8] = {};
#pragma unroll
    for (int k0 = 0; k0 < Hh; k0 += 32) {
        float4 u0 = *(const float4*)(xfrow + k0);
        float4 u1 = *(const float4*)(xfrow + k0 + 4);
        union { bf16x8 v; u32 u[4]; } cv;
        cv.u[0] = pack2(u0.x, u0.y);
        cv.u[1] = pack2(u0.z, u0.w);
        cv.u[2] = pack2(u1.x, u1.y);
        cv.u[3] = pack2(u1.z, u1.w);
        bf16x8 a = cv.v;
#pragma unroll
        for (int t = 0; t < 8; t++) {
            bf16x8 b = *(const bf16x8*)(wt + (t * 16 + m) * 136 + k0 + q * 8);
            acc[t] = __builtin_amdgcn_mfma_f32_16x16x32_bf16(a, b, acc[t], 0, 0, 0);
        }
    }

    int orow0 = row0 + q * 4;
#pragma unroll
    for (int t = 0; t < 8; t++) {
#pragma unroll
        for (int r = 0; r < 4; r++) {
            int rr = orow0 + r;
            if (rr < Nn) Yh[rr * Hh + t * 16 + m] = f2bf(acc[t][r]);
        }
    }
}

// ---------------- fused BN-normalize + mean pool + MLP head: one block per graph ----------------
__global__ __launch_bounds__(128) void k_poolmlp(const u16* __restrict__ Ah,
                                                 const float* __restrict__ stats,
                                                 const float* __restrict__ gam,
                                                 const float* __restrict__ bet,
                                                 const int* __restrict__ gstart,
                                                 const float* __restrict__ W1,
                                                 const float* __restrict__ b1,
                                                 const float* __restrict__ W2,
                                                 const float* __restrict__ b2,
                                                 float* __restrict__ out) {
    int g = blockIdx.x;
    int c = threadIdx.x;
    __shared__ float p[Hh];
    __shared__ float hid[Hh];
    float mu = stats[c] * (1.0f / Nn);
    float var = stats[Hh + c] * (1.0f / Nn) - mu * mu;
    float sc = rsqrtf(var + EPSf) * gam[c];
    float sf = bet[c] - mu * sc;
    int s = gstart[g], e = gstart[g + 1];
    float sum0 = 0.0f, sum1 = 0.0f;
    int r = s;
    for (; r + 1 < e; r += 2) {
        float v0 = __uint_as_float((u32)Ah[r * Hh + c] << 16);
        float v1 = __uint_as_float((u32)Ah[(r + 1) * Hh + c] << 16);
        sum0 += fmaxf(v0 * sc + sf, 0.0f);
        sum1 += fmaxf(v1 * sc + sf, 0.0f);
    }
    if (r < e) {
        float v = __uint_as_float((u32)Ah[r * Hh + c] << 16);
        sum0 += fmaxf(v * sc + sf, 0.0f);
    }
    int n = e - s;
    p[c] = (sum0 + sum1) / (float)(n > 1 ? n : 1);
    __syncthreads();
    float acc = b1[c];
    for (int k = 0; k < Hh; k++) acc += p[k] * W1[k * Hh + c];
    hid[c] = fmaxf(acc, 0.0f);
    __syncthreads();
    if (c < Cc) {
        float acc2 = b2[c];
        for (int k = 0; k < Hh; k++) acc2 += hid[k] * W2[k * Cc + c];
        out[g * Cc + c] = acc2;
    }
}

extern "C" void kernel_launch(void* const* d_in, const int* in_sizes, int n_in,
                              void* d_out, int out_size, void* d_ws, size_t ws_size,
                              hipStream_t stream) {
    const float* x      = (const float*)d_in[0];
    const int*   ei     = (const int*)d_in[1];
    const int*   batch  = (const int*)d_in[2];
    const float* conv_w = (const float*)d_in[3];
    const float* conv_b = (const float*)d_in[4];
    const float* bn_g   = (const float*)d_in[5];
    const float* bn_b   = (const float*)d_in[6];
    const float* w1     = (const float*)d_in[7];
    const float* b1     = (const float*)d_in[8];
    const float* w2     = (const float*)d_in[9];
    const float* b2     = (const float*)d_in[10];
    float* out = (float*)d_out;

    u16*   Yh      = (u16*)d_ws;                  // N*H bf16 row-major (gemm out)
    u16*   Ah      = Yh + Nn * Hh;                // N*H bf16 row-major (gather out)
    u16*   WT      = Ah + Nn * Hh;                // 3*H*H bf16 (W^T)
    float* dis     = (float*)(WT + 3 * Hh * Hh);  // N
    float* stats3  = dis + Nn;                    // 3*2*H
    int*   rs      = (int*)(stats3 + 3 * 2 * Hh); // N+1 exclusive starts
    int*   gstart  = rs + Nn + 1;                 // G+1
    int*   bsum    = gstart + Gg + 1;             // NSB
    u32*   recs    = (u32*)(bsum + NSB);          // E packed 4B records
    u16*   rankL   = (u16*)(recs + Ee);           // E within-(block,node) ranks
    u32*   partials = (u32*)(rankL + Ee);         // NBH * NW packed partial hists
    u32*   base_off = partials + NBH * NW;        // NBH * NW packed excl. offsets

    // ---- prologue + atomic-free CSR build (6 launches) ----
    k_pre<<<3, 256, 0, stream>>>(conv_w, WT, stats3);
    k_gemm<<<(Nn + 63) / 64, 256, 0, stream>>>(nullptr, x, WT, Yh,
                                               nullptr, nullptr, nullptr, 2);
    k_hist<<<NBH, 1024, 0, stream>>>(ei + Ee, rankL, partials);
    k_scan1<<<NSB, 256, 0, stream>>>(partials, base_off, rs, bsum, dis, batch, gstart);
    k_scan2<<<(Nn + 255) / 256, 256, 0, stream>>>(rs, bsum);
    k_fill<<<(Ee + 255) / 256, 256, 0, stream>>>(ei, rs, rankL, base_off, dis, recs);

    // ---- cooperative layer-loop megakernel (1 launch, replaces 8) ----
    void* kargs[10] = {(void*)&Yh, (void*)&Ah, (void*)&dis, (void*)&conv_b,
                       (void*)&rs, (void*)&recs, (void*)&stats3,
                       (void*)&bn_g, (void*)&bn_b, (void*)&WT};
    hipError_t cerr = hipLaunchCooperativeKernel((const void*)k_layers,
                                                 dim3(LGRID), dim3(256),
                                                 kargs, 0, stream);
    if (cerr != hipSuccess) {
        // fallback: discrete launches (round-6 structure)
        for (int l = 0; l < 3; l++) {
            k_gather<<<(Nn + 3) / 4, 256, 0, stream>>>(Yh, dis, conv_b + l * Hh, rs,
                                                       recs, Ah);
            k_stats<<<256, 256, 0, stream>>>(Ah, stats3 + l * 2 * Hh);
            if (l < 2) {
                k_gemm<<<(Nn + 63) / 64, 256, 0, stream>>>(Ah, nullptr,
                                                           WT + (l + 1) * Hh * Hh, Yh,
                                                           stats3 + l * 2 * Hh,
                                                           bn_g + l * Hh, bn_b + l * Hh, 1);
            }
        }
    }

    k_poolmlp<<<Gg, 128, 0, stream>>>(Ah, stats3 + 2 * 2 * Hh, bn_g + 2 * Hh,
                                      bn_b + 2 * Hh, gstart, w1, b1, w2, b2, out);
}

// Round 8
// 339.467 us; speedup vs baseline: 3.4210x; 3.4210x over previous
//
#include <hip/hip_runtime.h>

#define Nn 50000
#define Ee 800000
#define Gg 1000
#define Hh 128
#define Cc 6
#define EPSf 1e-5f
#define SB 1024                       // elements per scan block
#define NSB ((Nn + SB - 1) / SB)      // 49
#define NBH 64                        // histogram blocks
#define EPB (Ee / NBH)                // 12500 edges per histogram block
#define NW (Nn / 2)                   // 25000 packed u16-pair words
#define HWH (NW / 2)                  // 12500 words per half-pass (50 KB LDS)
#define GT ((Nn + 63) / 64)           // 782 gemm tiles

typedef unsigned short u16;
typedef unsigned int u32;
typedef __attribute__((ext_vector_type(8))) short bf16x8;
typedef __attribute__((ext_vector_type(4))) float f32x4;
typedef __attribute__((ext_vector_type(4))) unsigned int u32x4;

static __device__ inline u16 f2bf(float f) {
    u32 u = __float_as_uint(f);
    u32 r = (u + 0x7fffu + ((u >> 16) & 1u)) >> 16;   // RNE
    return (u16)r;
}
static __device__ inline float bf_lo(u32 v) { return __uint_as_float(v << 16); }
static __device__ inline float bf_hi(u32 v) { return __uint_as_float(v & 0xffff0000u); }
static __device__ inline u32 pack2(float a, float b) {
    return ((u32)f2bf(b) << 16) | (u32)f2bf(a);
}

// ---------------- prologue A: W->bf16 W^T (3 blocks) + zero stats ----------------
__global__ __launch_bounds__(256) void k_pre(const float* __restrict__ W3,
                                             u16* __restrict__ WT3,
                                             float* __restrict__ stats3) {
    __shared__ u16 tbuf[Hh * 136];
    int l = blockIdx.x;                // 3 blocks, one per layer
    int tid = threadIdx.x;
    stats3[l * 256 + tid] = 0.0f;      // 3*256 = 768 floats
    const float* W = W3 + l * Hh * Hh;
    u16* WT = WT3 + l * Hh * Hh;
#pragma unroll
    for (int i = 0; i < 16; i++) {
        int v = tid + 256 * i;         // float4 idx over 4096
        int r = v >> 5, c4 = v & 31;
        float4 d = ((const float4*)W)[v];
        u16* p = tbuf + r * 136 + c4 * 4;
        p[0] = f2bf(d.x); p[1] = f2bf(d.y); p[2] = f2bf(d.z); p[3] = f2bf(d.w);
    }
    __syncthreads();
#pragma unroll
    for (int i = 0; i < 64; i++) {
        int o = tid + 256 * i;         // u16 idx over 16384
        int n = o >> 7, k = o & 127;
        WT[o] = tbuf[k * 136 + n];
    }
}

// ---------------- fused prologue B: {in-degree LDS histogram} || {layer-0 GEMM} ----------------
// blocks [0..63]:   LDS-privatized histogram (zero global atomics), 256 thr
// blocks [64..845]: layer-0 MFMA GEMM, f32 A load + in-register bf16 cast
// Independent data streams -> true overlap inside one launch.
__global__ __launch_bounds__(256) void k_pro(const int* __restrict__ ei_dst,
                                             u16* __restrict__ rankL,
                                             u32* __restrict__ partials,
                                             const float* __restrict__ Xf,
                                             const u16* __restrict__ WT0,
                                             u16* __restrict__ Yh) {
    extern __shared__ __align__(16) unsigned char smem[];   // 50000 B dynamic
    int bid = blockIdx.x, tid = threadIdx.x;

    if (bid < NBH) {
        // ---- histogram branch ----
        u32* h = (u32*)smem;          // HWH words (50 KB)
        int e0 = bid * EPB;
        u32* P = partials + bid * NW;
#pragma unroll 1
        for (int half = 0; half < 2; half++) {
            int wlo = half * HWH;
            for (int i = tid; i < HWH; i += 256) h[i] = 0u;
            __syncthreads();
            for (int i = tid; i < EPB; i += 256) {
                int d = ei_dst[e0 + i];
                int w = d >> 1;
                if (w >= wlo && w < wlo + HWH) {
                    u32 old = atomicAdd(&h[w - wlo], (d & 1) ? 65536u : 1u);
                    rankL[e0 + i] = (u16)((d & 1) ? (old >> 16) : (old & 0xffffu));
                }
            }
            __syncthreads();
            for (int i = tid; i < HWH; i += 256) P[wlo + i] = h[i];
            __syncthreads();
        }
        return;
    }

    // ---- layer-0 GEMM branch ----
    u16* wt = (u16*)smem;             // Hh*136 u16 = 34816 B
#pragma unroll
    for (int i = 0; i < 8; i++) {
        int v = tid + 256 * i;        // uint4 idx over 2048
        int n = v >> 4, k8 = v & 15;
        uint4 d = ((const uint4*)WT0)[v];
        *((uint4*)(wt + n * 136 + k8 * 8)) = d;
    }
    __syncthreads();

    int tile = bid - NBH;
    int wv = tid >> 6, lane = tid & 63;
    int m = lane & 15, q = lane >> 4;
    int row0 = tile * 64 + wv * 16;
    int lrow = row0 + m;
    if (lrow >= Nn) lrow = Nn - 1;    // clamp load row; stores guarded
    const float* xfrow = Xf + lrow * Hh + q * 8;

    f32x4 acc[8] = {};
#pragma unroll
    for (int k0 = 0; k0 < Hh; k0 += 32) {
        float4 u0 = *(const float4*)(xfrow + k0);
        float4 u1 = *(const float4*)(xfrow + k0 + 4);
        union { bf16x8 v; u32 u[4]; } cv;
        cv.u[0] = pack2(u0.x, u0.y);
        cv.u[1] = pack2(u0.z, u0.w);
        cv.u[2] = pack2(u1.x, u1.y);
        cv.u[3] = pack2(u1.z, u1.w);
        bf16x8 a = cv.v;
#pragma unroll
        for (int t = 0; t < 8; t++) {
            bf16x8 b = *(const bf16x8*)(wt + (t * 16 + m) * 136 + k0 + q * 8);
            acc[t] = __builtin_amdgcn_mfma_f32_16x16x32_bf16(a, b, acc[t], 0, 0, 0);
        }
    }

    int orow0 = row0 + q * 4;
#pragma unroll
    for (int t = 0; t < 8; t++) {
#pragma unroll
        for (int r = 0; r < 4; r++) {
            int rr = orow0 + r;
            if (rr < Nn) Yh[rr * Hh + t * 16 + m] = f2bf(acc[t][r]);
        }
    }
}

// ---------------- scan phase 1 (fused partials merge) + dis + gstart ----------------
// Writes LOCAL exclusive starts rs[] + per-block totals bsum[]; rs[Nn] = last
// block's local total (globalized later via lboff).
__global__ __launch_bounds__(256) void k_scan1(const u32* __restrict__ partials,
                                               u32* __restrict__ base_off,
                                               int* __restrict__ rs,
                                               int* __restrict__ bsum,
                                               float* __restrict__ dis,
                                               const int* __restrict__ batch,
                                               int* __restrict__ gstart) {
    __shared__ int ts[256];
    int b = blockIdx.x;
    int t = threadIdx.x;
    int base = b * SB + t * 4;        // 4 nodes = 2 packed words
    int v[4] = {0, 0, 0, 0};
    if (base < Nn) {                  // Nn%4==0 so whole quad in-bounds
        int w0 = base >> 1;
        u32 run0 = 0, run1 = 0;
#pragma unroll 8
        for (int b2 = 0; b2 < NBH; b2++) {
            u32 p0 = partials[b2 * NW + w0];
            u32 p1 = partials[b2 * NW + w0 + 1];
            base_off[b2 * NW + w0] = run0;
            base_off[b2 * NW + w0 + 1] = run1;
            run0 += p0; run1 += p1;
        }
        v[0] = (int)(run0 & 0xffffu); v[1] = (int)(run0 >> 16);
        v[2] = (int)(run1 & 0xffffu); v[3] = (int)(run1 >> 16);
        dis[base]     = rsqrtf((float)v[0] + 1.0f);
        dis[base + 1] = rsqrtf((float)v[1] + 1.0f);
        dis[base + 2] = rsqrtf((float)v[2] + 1.0f);
        dis[base + 3] = rsqrtf((float)v[3] + 1.0f);
    }
    int g = b * 256 + t;
    if (g <= Gg) {
        int lo = 0, hi = Nn;
        while (lo < hi) {
            int mid = (lo + hi) >> 1;
            if (batch[mid] < g) lo = mid + 1; else hi = mid;
        }
        gstart[g] = lo;
    }
    int tsum = v[0] + v[1] + v[2] + v[3];
    ts[t] = tsum;
    __syncthreads();
    for (int off = 1; off < 256; off <<= 1) {
        int x = (t >= off) ? ts[t - off] : 0;
        __syncthreads();
        ts[t] += x;
        __syncthreads();
    }
    int run = (t == 0) ? 0 : ts[t - 1];
    if (t == 255) {
        bsum[b] = ts[255];
        if (b == NSB - 1) rs[Nn] = ts[255];   // local end of last block
    }
#pragma unroll
    for (int j = 0; j < 4; j++) {
        int i = base + j;
        if (i < Nn) { rs[i] = run; run += v[j]; }
    }
}

// ---------------- counting-sort fill (absorbs scan2): ATOMIC-FREE ----------------
// Per-block redundant mini-scan of bsum -> lboff; slot = rs[d]+lboff+boff+rank.
// Blocks 0..195 also emit the globalized rs2[] (incl. rs2[Nn]=Ee) for the gather.
__global__ __launch_bounds__(256) void k_fill(const int* __restrict__ ei,
                                              const int* __restrict__ rs,
                                              const int* __restrict__ bsum,
                                              int* __restrict__ rs2,
                                              const u16* __restrict__ rankL,
                                              const u32* __restrict__ base_off,
                                              const float* __restrict__ dis,
                                              u32* __restrict__ recs) {
    __shared__ int lboff[NSB];
    int t = threadIdx.x;
    if (t < 64) {
        int orig = (t < NSB) ? bsum[t] : 0;
        int v = orig;
#pragma unroll
        for (int off = 1; off < 64; off <<= 1) {
            int u = __shfl_up(v, off, 64);
            if (t >= off) v += u;
        }
        if (t < NSB) lboff[t] = v - orig;   // exclusive over scan blocks
    }
    __syncthreads();

    int gi = blockIdx.x * 256 + t;
    if (gi <= Nn) rs2[gi] = rs[gi] + lboff[gi >> 10];   // blocks 0..195 active here

    int e = gi;
    if (e >= Ee) return;
    int s = ei[e];
    int d = ei[Ee + e];
    int blk = e / EPB;
    u32 bo = base_off[blk * NW + (d >> 1)];
    int rank = (int)rankL[e] + (int)((d & 1) ? (bo >> 16) : (bo & 0xffffu));
    int slot = rs[d] + lboff[d >> 10] + rank;
    float w = dis[s] * dis[d];
    recs[slot] = ((u32)f2bf(w) << 16) | (u32)s;   // s < 50000 < 65536
}

// ---------------- CSR gather: one wave/node, 4 edges per dwordx4 load ----------------
__global__ __launch_bounds__(256) void k_gather(const u16* __restrict__ Yh,
                                                const float* __restrict__ dis,
                                                const float* __restrict__ bias,
                                                const int* __restrict__ rs2,
                                                const u32* __restrict__ recs,
                                                u16* __restrict__ Ah) {
    int node = blockIdx.x * 4 + (threadIdx.x >> 6);
    if (node >= Nn) return;
    int lane = threadIdx.x & 63;
    int lg = lane >> 4;               // edge slot within quad
    int lc = lane & 15;               // uint4 column within row

    const uint4* rows4 = (const uint4*)Yh;    // row = 16 uint4 = 256 B

    float acc[8] = {0.f, 0.f, 0.f, 0.f, 0.f, 0.f, 0.f, 0.f};

    int beg = rs2[node];
    int end = rs2[node + 1];

    for (int base = beg; base < end; base += 64) {
        int me = base + lane;
        u32 myrec = recs[me < end ? me : end - 1];   // one coalesced load / 64 edges
        int cnt = end - base;
        if (cnt > 64) cnt = 64;
        for (int i0 = 0; i0 < cnt; i0 += 16) {
            u32 rr[4]; float ww[4]; uint4 vv[4];
#pragma unroll
            for (int j = 0; j < 4; j++) {
                int si = i0 + j * 4 + lg;
                int sc = si < cnt ? si : cnt - 1;
                u32 rec = __shfl(myrec, sc, 64);
                rr[j] = rec & 0xffffu;
                ww[j] = (si < cnt) ? __uint_as_float(rec & 0xffff0000u) : 0.0f;
            }
#pragma unroll
            for (int j = 0; j < 4; j++) vv[j] = rows4[rr[j] * 16 + lc];
#pragma unroll
            for (int j = 0; j < 4; j++) {
                acc[0] += bf_lo(vv[j].x) * ww[j];
                acc[1] += bf_hi(vv[j].x) * ww[j];
                acc[2] += bf_lo(vv[j].y) * ww[j];
                acc[3] += bf_hi(vv[j].y) * ww[j];
                acc[4] += bf_lo(vv[j].z) * ww[j];
                acc[5] += bf_hi(vv[j].z) * ww[j];
                acc[6] += bf_lo(vv[j].w) * ww[j];
                acc[7] += bf_hi(vv[j].w) * ww[j];
            }
        }
    }
#pragma unroll
    for (int k = 0; k < 8; k++) {
        acc[k] += __shfl_xor(acc[k], 16, 64);
        acc[k] += __shfl_xor(acc[k], 32, 64);
    }
    if (lg == 0) {
        float sn = dis[node];
        sn = sn * sn;
        uint4 hv = rows4[node * 16 + lc];
        const float4* bq = (const float4*)bias;
        float4 b0 = bq[lc * 2];
        float4 b1 = bq[lc * 2 + 1];
        acc[0] = acc[0] + bf_lo(hv.x) * sn + b0.x;
        acc[1] = acc[1] + bf_hi(hv.x) * sn + b0.y;
        acc[2] = acc[2] + bf_lo(hv.y) * sn + b0.z;
        acc[3] = acc[3] + bf_hi(hv.y) * sn + b0.w;
        acc[4] = acc[4] + bf_lo(hv.z) * sn + b1.x;
        acc[5] = acc[5] + bf_hi(hv.z) * sn + b1.y;
        acc[6] = acc[6] + bf_lo(hv.w) * sn + b1.z;
        acc[7] = acc[7] + bf_hi(hv.w) * sn + b1.w;
        u32x4 o;
        o.x = pack2(acc[0], acc[1]);
        o.y = pack2(acc[2], acc[3]);
        o.z = pack2(acc[4], acc[5]);
        o.w = pack2(acc[6], acc[7]);
        __builtin_nontemporal_store(o, (u32x4*)Ah + node * 16 + lc);
    }
}

// ---------------- BN stats from row-major bf16: per-channel sum & sumsq ----------------
__global__ __launch_bounds__(256) void k_stats(const u16* __restrict__ Ah,
                                               float* __restrict__ stats) {
    __shared__ float sh[4][256];
    int t = threadIdx.x;
    int jc = t & 63, ro = t >> 6;         // jc: u32-column (channels 2jc,2jc+1)
    const u32* col = (const u32*)Ah + jc;
    float sx = 0.f, sy = 0.f, qx = 0.f, qy = 0.f;
    for (int r = blockIdx.x * 16 + ro * 4; r < Nn; r += 4096) {
        u32 v[4];
#pragma unroll
        for (int k = 0; k < 4; k++) {
            int rr = r + k;
            v[k] = (rr < Nn) ? col[rr * 64] : 0u;
        }
#pragma unroll
        for (int k = 0; k < 4; k++) {
            float a = bf_lo(v[k]), b = bf_hi(v[k]);
            sx += a; sy += b; qx += a * a; qy += b * b;
        }
    }
    sh[0][t] = sx; sh[1][t] = sy; sh[2][t] = qx; sh[3][t] = qy;
    __syncthreads();
    if (t < 64) {
        sx = sh[0][t] + sh[0][t + 64] + sh[0][t + 128] + sh[0][t + 192];
        sy = sh[1][t] + sh[1][t + 64] + sh[1][t + 128] + sh[1][t + 192];
        qx = sh[2][t] + sh[2][t + 64] + sh[2][t + 128] + sh[2][t + 192];
        qy = sh[3][t] + sh[3][t + 64] + sh[3][t + 128] + sh[3][t + 192];
        atomicAdd(&stats[2 * t], sx);
        atomicAdd(&stats[2 * t + 1], sy);
        atomicAdd(&stats[Hh + 2 * t], qx);
        atomicAdd(&stats[Hh + 2 * t + 1], qy);
    }
}

// ---------------- MFMA GEMM, fused BN-normalize+ReLU on A (layers 1,2) ----------------
__global__ __launch_bounds__(256) void k_gemm(const u16* __restrict__ Xin,
                                              const u16* __restrict__ WT,
                                              u16* __restrict__ Yh,
                                              const float* __restrict__ stats,
                                              const float* __restrict__ gam,
                                              const float* __restrict__ bet) {
    __shared__ u16 wt[Hh * 136];
    __shared__ float s_scale[Hh], s_shift[Hh];
    int tid = threadIdx.x;

    if (tid < Hh) {
        float mu = stats[tid] * (1.0f / Nn);
        float var = stats[Hh + tid] * (1.0f / Nn) - mu * mu;
        float sc = rsqrtf(var + EPSf) * gam[tid];
        s_scale[tid] = sc;
        s_shift[tid] = bet[tid] - mu * sc;
    }
#pragma unroll
    for (int i = 0; i < 8; i++) {
        int v = tid + 256 * i;            // uint4 idx over 2048
        int n = v >> 4, k8 = v & 15;
        uint4 d = ((const uint4*)WT)[v];
        *((uint4*)(wt + n * 136 + k8 * 8)) = d;
    }
    __syncthreads();

    int wv = tid >> 6, lane = tid & 63;
    int m = lane & 15, q = lane >> 4;
    int row0 = blockIdx.x * 64 + wv * 16;
    int lrow = row0 + m;
    if (lrow >= Nn) lrow = Nn - 1;        // clamp load row; stores guarded
    const u16* xrow = Xin + lrow * Hh + q * 8;

    f32x4 acc[8] = {};
#pragma unroll
    for (int k0 = 0; k0 < Hh; k0 += 32) {
        int cb = k0 + q * 8;
        uint4 p = *(const uint4*)(xrow + k0);
        float4 sc0 = *(const float4*)(s_scale + cb);
        float4 sc1 = *(const float4*)(s_scale + cb + 4);
        float4 sh0 = *(const float4*)(s_shift + cb);
        float4 sh1 = *(const float4*)(s_shift + cb + 4);
        float f0 = fmaxf(bf_lo(p.x) * sc0.x + sh0.x, 0.0f);
        float f1 = fmaxf(bf_hi(p.x) * sc0.y + sh0.y, 0.0f);
        float f2 = fmaxf(bf_lo(p.y) * sc0.z + sh0.z, 0.0f);
        float f3 = fmaxf(bf_hi(p.y) * sc0.w + sh0.w, 0.0f);
        float f4 = fmaxf(bf_lo(p.z) * sc1.x + sh1.x, 0.0f);
        float f5 = fmaxf(bf_hi(p.z) * sc1.y + sh1.y, 0.0f);
        float f6 = fmaxf(bf_lo(p.w) * sc1.z + sh1.z, 0.0f);
        float f7 = fmaxf(bf_hi(p.w) * sc1.w + sh1.w, 0.0f);
        union { bf16x8 v; u32 u[4]; } cv;
        cv.u[0] = pack2(f0, f1);
        cv.u[1] = pack2(f2, f3);
        cv.u[2] = pack2(f4, f5);
        cv.u[3] = pack2(f6, f7);
        bf16x8 a = cv.v;
#pragma unroll
        for (int t = 0; t < 8; t++) {
            bf16x8 b = *(const bf16x8*)(wt + (t * 16 + m) * 136 + k0 + q * 8);
            acc[t] = __builtin_amdgcn_mfma_f32_16x16x32_bf16(a, b, acc[t], 0, 0, 0);
        }
    }

    int orow0 = row0 + q * 4;
#pragma unroll
    for (int t = 0; t < 8; t++) {
#pragma unroll
        for (int r = 0; r < 4; r++) {
            int rr = orow0 + r;
            if (rr < Nn) Yh[rr * Hh + t * 16 + m] = f2bf(acc[t][r]);
        }
    }
}

// ---------------- fused BN-normalize + mean pool + MLP head ----------------
__global__ __launch_bounds__(128) void k_poolmlp(const u16* __restrict__ Ah,
                                                 const float* __restrict__ stats,
                                                 const float* __restrict__ gam,
                                                 const float* __restrict__ bet,
                                                 const int* __restrict__ gstart,
                                                 const float* __restrict__ W1,
                                                 const float* __restrict__ b1,
                                                 const float* __restrict__ W2,
                                                 const float* __restrict__ b2,
                                                 float* __restrict__ out) {
    int g = blockIdx.x;
    int c = threadIdx.x;
    __shared__ float p[Hh];
    __shared__ float hid[Hh];
    float mu = stats[c] * (1.0f / Nn);
    float var = stats[Hh + c] * (1.0f / Nn) - mu * mu;
    float sc = rsqrtf(var + EPSf) * gam[c];
    float sf = bet[c] - mu * sc;
    int s = gstart[g], e = gstart[g + 1];
    float sum0 = 0.0f, sum1 = 0.0f;
    int r = s;
    for (; r + 1 < e; r += 2) {
        float v0 = __uint_as_float((u32)Ah[r * Hh + c] << 16);
        float v1 = __uint_as_float((u32)Ah[(r + 1) * Hh + c] << 16);
        sum0 += fmaxf(v0 * sc + sf, 0.0f);
        sum1 += fmaxf(v1 * sc + sf, 0.0f);
    }
    if (r < e) {
        float v = __uint_as_float((u32)Ah[r * Hh + c] << 16);
        sum0 += fmaxf(v * sc + sf, 0.0f);
    }
    int n = e - s;
    p[c] = (sum0 + sum1) / (float)(n > 1 ? n : 1);
    __syncthreads();
    float acc = b1[c];
    for (int k = 0; k < Hh; k++) acc += p[k] * W1[k * Hh + c];
    hid[c] = fmaxf(acc, 0.0f);
    __syncthreads();
    if (c < Cc) {
        float acc2 = b2[c];
        for (int k = 0; k < Hh; k++) acc2 += hid[k] * W2[k * Cc + c];
        out[g * Cc + c] = acc2;
    }
}

extern "C" void kernel_launch(void* const* d_in, const int* in_sizes, int n_in,
                              void* d_out, int out_size, void* d_ws, size_t ws_size,
                              hipStream_t stream) {
    const float* x      = (const float*)d_in[0];
    const int*   ei     = (const int*)d_in[1];
    const int*   batch  = (const int*)d_in[2];
    const float* conv_w = (const float*)d_in[3];
    const float* conv_b = (const float*)d_in[4];
    const float* bn_g   = (const float*)d_in[5];
    const float* bn_b   = (const float*)d_in[6];
    const float* w1     = (const float*)d_in[7];
    const float* b1     = (const float*)d_in[8];
    const float* w2     = (const float*)d_in[9];
    const float* b2     = (const float*)d_in[10];
    float* out = (float*)d_out;

    u16*   Yh      = (u16*)d_ws;                  // N*H bf16 row-major (gemm out)
    u16*   Ah      = Yh + Nn * Hh;                // N*H bf16 row-major (gather out)
    u16*   WT      = Ah + Nn * Hh;                // 3*H*H bf16 (W^T)
    float* dis     = (float*)(WT + 3 * Hh * Hh);  // N
    float* stats3  = dis + Nn;                    // 3*2*H
    int*   rs      = (int*)(stats3 + 3 * 2 * Hh); // N+1 local-exclusive starts
    int*   rs2     = rs + Nn + 1;                 // N+1 globalized starts
    int*   gstart  = rs2 + Nn + 1;                // G+1
    int*   bsum    = gstart + Gg + 1;             // NSB
    u32*   recs    = (u32*)(bsum + NSB);          // E packed 4B records
    u16*   rankL   = (u16*)(recs + Ee);           // E within-(block,node) ranks
    u32*   partials = (u32*)(rankL + Ee);         // NBH * NW packed partial hists
    u32*   base_off = partials + NBH * NW;        // NBH * NW packed excl. offsets

    // ---- prologue: W^T; then {histogram || layer-0 GEMM} fused; CSR build ----
    k_pre<<<3, 256, 0, stream>>>(conv_w, WT, stats3);
    k_pro<<<NBH + GT, 256, 50000, stream>>>(ei + Ee, rankL, partials, x, WT, Yh);
    k_scan1<<<NSB, 256, 0, stream>>>(partials, base_off, rs, bsum, dis, batch, gstart);
    k_fill<<<(Ee + 255) / 256, 256, 0, stream>>>(ei, rs, bsum, rs2, rankL, base_off,
                                                 dis, recs);

    for (int l = 0; l < 3; l++) {
        k_gather<<<(Nn + 3) / 4, 256, 0, stream>>>(Yh, dis, conv_b + l * Hh, rs2,
                                                   recs, Ah);
        k_stats<<<256, 256, 0, stream>>>(Ah, stats3 + l * 2 * Hh);
        if (l < 2) {
            k_gemm<<<(Nn + 63) / 64, 256, 0, stream>>>(Ah, WT + (l + 1) * Hh * Hh, Yh,
                                                       stats3 + l * 2 * Hh,
                                                       bn_g + l * Hh, bn_b + l * Hh);
        }
    }

    k_poolmlp<<<Gg, 128, 0, stream>>>(Ah, stats3 + 2 * 2 * Hh, bn_g + 2 * Hh,
                                      bn_b + 2 * Hh, gstart, w1, b1, w2, b2, out);
}

// Round 9
// 289.494 us; speedup vs baseline: 4.0116x; 1.1726x over previous
//
#include <hip/hip_runtime.h>

#define Nn 50000
#define Ee 800000
#define Gg 1000
#define Hh 128
#define Cc 6
#define EPSf 1e-5f
#define SB 1024                       // elements per scan block
#define NSB ((Nn + SB - 1) / SB)      // 49
#define NBH 64                        // histogram blocks
#define EPB (Ee / NBH)                // 12500 edges per histogram block
#define NW (Nn / 2)                   // 25000 packed u16-pair words
#define HWH (NW / 2)                  // 12500 words per half-pass (50 KB LDS)
#define GT ((Nn + 63) / 64)           // 782 gemm tiles
#define GT4 ((GT + 3) / 4)            // 196 four-tile gemm groups
#define NREP 8                        // stats atomic-spread replicas
#define STS (NREP * 2 * Hh)           // 2048 floats per layer's stats slab

typedef unsigned short u16;
typedef unsigned int u32;
typedef __attribute__((ext_vector_type(8))) short bf16x8;
typedef __attribute__((ext_vector_type(4))) float f32x4;
typedef __attribute__((ext_vector_type(4))) unsigned int u32x4;

static __device__ inline u16 f2bf(float f) {
    u32 u = __float_as_uint(f);
    u32 r = (u + 0x7fffu + ((u >> 16) & 1u)) >> 16;   // RNE
    return (u16)r;
}
static __device__ inline float bf_lo(u32 v) { return __uint_as_float(v << 16); }
static __device__ inline float bf_hi(u32 v) { return __uint_as_float(v & 0xffff0000u); }
static __device__ inline u32 pack2(float a, float b) {
    return ((u32)f2bf(b) << 16) | (u32)f2bf(a);
}

// ---------------- prologue A: W->bf16 W^T (3 blocks) + zero stats slabs ----------------
__global__ __launch_bounds__(256) void k_pre(const float* __restrict__ W3,
                                             u16* __restrict__ WT3,
                                             float* __restrict__ stats3) {
    __shared__ u16 tbuf[Hh * 136];
    int l = blockIdx.x;                // 3 blocks, one per layer
    int tid = threadIdx.x;
#pragma unroll
    for (int i = 0; i < 8; i++) stats3[l * STS + tid + 256 * i] = 0.0f;
    const float* W = W3 + l * Hh * Hh;
    u16* WT = WT3 + l * Hh * Hh;
#pragma unroll
    for (int i = 0; i < 16; i++) {
        int v = tid + 256 * i;         // float4 idx over 4096
        int r = v >> 5, c4 = v & 31;
        float4 d = ((const float4*)W)[v];
        u16* p = tbuf + r * 136 + c4 * 4;
        p[0] = f2bf(d.x); p[1] = f2bf(d.y); p[2] = f2bf(d.z); p[3] = f2bf(d.w);
    }
    __syncthreads();
#pragma unroll
    for (int i = 0; i < 64; i++) {
        int o = tid + 256 * i;         // u16 idx over 16384
        int n = o >> 7, k = o & 127;
        WT[o] = tbuf[k * 136 + n];
    }
}

// ---------------- fused prologue B: {histogram @1024thr} || {layer-0 GEMM, 4 tiles/block} ----------------
// blocks [0..63]:        LDS histogram, full 1024 threads (round-6 k_hist shape)
// blocks [64..64+195]:   layer-0 GEMM; wt staged once per block, each 256-thr
//                        quarter computes one 64-row tile -> 16 waves/block.
__global__ __launch_bounds__(1024) void k_pro(const int* __restrict__ ei_dst,
                                              u16* __restrict__ rankL,
                                              u32* __restrict__ partials,
                                              const float* __restrict__ Xf,
                                              const u16* __restrict__ WT0,
                                              u16* __restrict__ Yh) {
    extern __shared__ __align__(16) unsigned char smem[];   // 50000 B dynamic
    int bid = blockIdx.x, tid = threadIdx.x;

    if (bid < NBH) {
        // ---- histogram branch (1024 threads) ----
        u32* h = (u32*)smem;          // HWH words (50 KB)
        int e0 = bid * EPB;
        u32* P = partials + bid * NW;
#pragma unroll 1
        for (int half = 0; half < 2; half++) {
            int wlo = half * HWH;
            for (int i = tid; i < HWH; i += 1024) h[i] = 0u;
            __syncthreads();
            for (int i = tid; i < EPB; i += 1024) {
                int d = ei_dst[e0 + i];
                int w = d >> 1;
                if (w >= wlo && w < wlo + HWH) {
                    u32 old = atomicAdd(&h[w - wlo], (d & 1) ? 65536u : 1u);
                    rankL[e0 + i] = (u16)((d & 1) ? (old >> 16) : (old & 0xffffu));
                }
            }
            __syncthreads();
            for (int i = tid; i < HWH; i += 1024) P[wlo + i] = h[i];
            __syncthreads();
        }
        return;
    }

    // ---- layer-0 GEMM branch: stage wt once, 4 tiles per block ----
    u16* wt = (u16*)smem;             // Hh*136 u16 = 34816 B
#pragma unroll
    for (int i = 0; i < 2; i++) {
        int v = tid + 1024 * i;       // uint4 idx over 2048
        int n = v >> 4, k8 = v & 15;
        uint4 d = ((const uint4*)WT0)[v];
        *((uint4*)(wt + n * 136 + k8 * 8)) = d;
    }
    __syncthreads();

    int tile = (bid - NBH) * 4 + (tid >> 8);
    if (tile >= GT) return;
    int t256 = tid & 255;
    int wv = t256 >> 6, lane = t256 & 63;
    int m = lane & 15, q = lane >> 4;
    int row0 = tile * 64 + wv * 16;
    int lrow = row0 + m;
    if (lrow >= Nn) lrow = Nn - 1;    // clamp load row; stores guarded
    const float* xfrow = Xf + lrow * Hh + q * 8;

    f32x4 acc[8] = {};
#pragma unroll
    for (int k0 = 0; k0 < Hh; k0 += 32) {
        float4 u0 = *(const float4*)(xfrow + k0);
        float4 u1 = *(const float4*)(xfrow + k0 + 4);
        union { bf16x8 v; u32 u[4]; } cv;
        cv.u[0] = pack2(u0.x, u0.y);
        cv.u[1] = pack2(u0.z, u0.w);
        cv.u[2] = pack2(u1.x, u1.y);
        cv.u[3] = pack2(u1.z, u1.w);
        bf16x8 a = cv.v;
#pragma unroll
        for (int t = 0; t < 8; t++) {
            bf16x8 b = *(const bf16x8*)(wt + (t * 16 + m) * 136 + k0 + q * 8);
            acc[t] = __builtin_amdgcn_mfma_f32_16x16x32_bf16(a, b, acc[t], 0, 0, 0);
        }
    }

    int orow0 = row0 + q * 4;
#pragma unroll
    for (int t = 0; t < 8; t++) {
#pragma unroll
        for (int r = 0; r < 4; r++) {
            int rr = orow0 + r;
            if (rr < Nn) Yh[rr * Hh + t * 16 + m] = f2bf(acc[t][r]);
        }
    }
}

// ---------------- scan phase 1 (fused partials merge) + dis + gstart ----------------
__global__ __launch_bounds__(256) void k_scan1(const u32* __restrict__ partials,
                                               u32* __restrict__ base_off,
                                               int* __restrict__ rs,
                                               int* __restrict__ bsum,
                                               float* __restrict__ dis,
                                               const int* __restrict__ batch,
                                               int* __restrict__ gstart) {
    __shared__ int ts[256];
    int b = blockIdx.x;
    int t = threadIdx.x;
    int base = b * SB + t * 4;        // 4 nodes = 2 packed words
    int v[4] = {0, 0, 0, 0};
    if (base < Nn) {                  // Nn%4==0 so whole quad in-bounds
        int w0 = base >> 1;
        u32 run0 = 0, run1 = 0;
#pragma unroll 8
        for (int b2 = 0; b2 < NBH; b2++) {
            u32 p0 = partials[b2 * NW + w0];
            u32 p1 = partials[b2 * NW + w0 + 1];
            base_off[b2 * NW + w0] = run0;
            base_off[b2 * NW + w0 + 1] = run1;
            run0 += p0; run1 += p1;
        }
        v[0] = (int)(run0 & 0xffffu); v[1] = (int)(run0 >> 16);
        v[2] = (int)(run1 & 0xffffu); v[3] = (int)(run1 >> 16);
        dis[base]     = rsqrtf((float)v[0] + 1.0f);
        dis[base + 1] = rsqrtf((float)v[1] + 1.0f);
        dis[base + 2] = rsqrtf((float)v[2] + 1.0f);
        dis[base + 3] = rsqrtf((float)v[3] + 1.0f);
    }
    int g = b * 256 + t;
    if (g <= Gg) {
        int lo = 0, hi = Nn;
        while (lo < hi) {
            int mid = (lo + hi) >> 1;
            if (batch[mid] < g) lo = mid + 1; else hi = mid;
        }
        gstart[g] = lo;
    }
    int tsum = v[0] + v[1] + v[2] + v[3];
    ts[t] = tsum;
    __syncthreads();
    for (int off = 1; off < 256; off <<= 1) {
        int x = (t >= off) ? ts[t - off] : 0;
        __syncthreads();
        ts[t] += x;
        __syncthreads();
    }
    int run = (t == 0) ? 0 : ts[t - 1];
    if (t == 255) {
        bsum[b] = ts[255];
        if (b == NSB - 1) rs[Nn] = ts[255];   // local end of last block
    }
#pragma unroll
    for (int j = 0; j < 4; j++) {
        int i = base + j;
        if (i < Nn) { rs[i] = run; run += v[j]; }
    }
}

// ---------------- counting-sort fill (absorbs scan2): ATOMIC-FREE ----------------
__global__ __launch_bounds__(256) void k_fill(const int* __restrict__ ei,
                                              const int* __restrict__ rs,
                                              const int* __restrict__ bsum,
                                              int* __restrict__ rs2,
                                              const u16* __restrict__ rankL,
                                              const u32* __restrict__ base_off,
                                              const float* __restrict__ dis,
                                              u32* __restrict__ recs) {
    __shared__ int lboff[NSB];
    int t = threadIdx.x;
    if (t < 64) {
        int orig = (t < NSB) ? bsum[t] : 0;
        int v = orig;
#pragma unroll
        for (int off = 1; off < 64; off <<= 1) {
            int u = __shfl_up(v, off, 64);
            if (t >= off) v += u;
        }
        if (t < NSB) lboff[t] = v - orig;   // exclusive over scan blocks
    }
    __syncthreads();

    int gi = blockIdx.x * 256 + t;
    if (gi <= Nn) rs2[gi] = rs[gi] + lboff[gi >> 10];   // blocks 0..195 active here

    int e = gi;
    if (e >= Ee) return;
    int s = ei[e];
    int d = ei[Ee + e];
    int blk = e / EPB;
    u32 bo = base_off[blk * NW + (d >> 1)];
    int rank = (int)rankL[e] + (int)((d & 1) ? (bo >> 16) : (bo & 0xffffu));
    int slot = rs[d] + lboff[d >> 10] + rank;
    float w = dis[s] * dis[d];
    recs[slot] = ((u32)f2bf(w) << 16) | (u32)s;   // s < 50000 < 65536
}

// ---------------- CSR gather: one wave/node, 4 edges per dwordx4 load ----------------
__global__ __launch_bounds__(256) void k_gather(const u16* __restrict__ Yh,
                                                const float* __restrict__ dis,
                                                const float* __restrict__ bias,
                                                const int* __restrict__ rs2,
                                                const u32* __restrict__ recs,
                                                u16* __restrict__ Ah) {
    int node = blockIdx.x * 4 + (threadIdx.x >> 6);
    if (node >= Nn) return;
    int lane = threadIdx.x & 63;
    int lg = lane >> 4;               // edge slot within quad
    int lc = lane & 15;               // uint4 column within row

    const uint4* rows4 = (const uint4*)Yh;    // row = 16 uint4 = 256 B

    float acc[8] = {0.f, 0.f, 0.f, 0.f, 0.f, 0.f, 0.f, 0.f};

    int beg = rs2[node];
    int end = rs2[node + 1];

    for (int base = beg; base < end; base += 64) {
        int me = base + lane;
        u32 myrec = recs[me < end ? me : end - 1];   // one coalesced load / 64 edges
        int cnt = end - base;
        if (cnt > 64) cnt = 64;
        for (int i0 = 0; i0 < cnt; i0 += 16) {
            u32 rr[4]; float ww[4]; uint4 vv[4];
#pragma unroll
            for (int j = 0; j < 4; j++) {
                int si = i0 + j * 4 + lg;
                int sc = si < cnt ? si : cnt - 1;
                u32 rec = __shfl(myrec, sc, 64);
                rr[j] = rec & 0xffffu;
                ww[j] = (si < cnt) ? __uint_as_float(rec & 0xffff0000u) : 0.0f;
            }
#pragma unroll
            for (int j = 0; j < 4; j++) vv[j] = rows4[rr[j] * 16 + lc];
#pragma unroll
            for (int j = 0; j < 4; j++) {
                acc[0] += bf_lo(vv[j].x) * ww[j];
                acc[1] += bf_hi(vv[j].x) * ww[j];
                acc[2] += bf_lo(vv[j].y) * ww[j];
                acc[3] += bf_hi(vv[j].y) * ww[j];
                acc[4] += bf_lo(vv[j].z) * ww[j];
                acc[5] += bf_hi(vv[j].z) * ww[j];
                acc[6] += bf_lo(vv[j].w) * ww[j];
                acc[7] += bf_hi(vv[j].w) * ww[j];
            }
        }
    }
#pragma unroll
    for (int k = 0; k < 8; k++) {
        acc[k] += __shfl_xor(acc[k], 16, 64);
        acc[k] += __shfl_xor(acc[k], 32, 64);
    }
    if (lg == 0) {
        float sn = dis[node];
        sn = sn * sn;
        uint4 hv = rows4[node * 16 + lc];
        const float4* bq = (const float4*)bias;
        float4 b0 = bq[lc * 2];
        float4 b1 = bq[lc * 2 + 1];
        acc[0] = acc[0] + bf_lo(hv.x) * sn + b0.x;
        acc[1] = acc[1] + bf_hi(hv.x) * sn + b0.y;
        acc[2] = acc[2] + bf_lo(hv.y) * sn + b0.z;
        acc[3] = acc[3] + bf_hi(hv.y) * sn + b0.w;
        acc[4] = acc[4] + bf_lo(hv.z) * sn + b1.x;
        acc[5] = acc[5] + bf_hi(hv.z) * sn + b1.y;
        acc[6] = acc[6] + bf_lo(hv.w) * sn + b1.z;
        acc[7] = acc[7] + bf_hi(hv.w) * sn + b1.w;
        u32x4 o;
        o.x = pack2(acc[0], acc[1]);
        o.y = pack2(acc[2], acc[3]);
        o.z = pack2(acc[4], acc[5]);
        o.w = pack2(acc[6], acc[7]);
        __builtin_nontemporal_store(o, (u32x4*)Ah + node * 16 + lc);
    }
}

// ---------------- BN stats: per-channel sum & sumsq, 8-way replica atomic spread ----------------
__global__ __launch_bounds__(256) void k_stats(const u16* __restrict__ Ah,
                                               float* __restrict__ stats) {
    __shared__ float sh[4][256];
    int t = threadIdx.x;
    int jc = t & 63, ro = t >> 6;         // jc: u32-column (channels 2jc,2jc+1)
    const u32* col = (const u32*)Ah + jc;
    float sx = 0.f, sy = 0.f, qx = 0.f, qy = 0.f;
    for (int r = blockIdx.x * 16 + ro * 4; r < Nn; r += 4096) {
        u32 v[4];
#pragma unroll
        for (int k = 0; k < 4; k++) {
            int rr = r + k;
            v[k] = (rr < Nn) ? col[rr * 64] : 0u;
        }
#pragma unroll
        for (int k = 0; k < 4; k++) {
            float a = bf_lo(v[k]), b = bf_hi(v[k]);
            sx += a; sy += b; qx += a * a; qy += b * b;
        }
    }
    sh[0][t] = sx; sh[1][t] = sy; sh[2][t] = qx; sh[3][t] = qy;
    __syncthreads();
    if (t < 64) {
        sx = sh[0][t] + sh[0][t + 64] + sh[0][t + 128] + sh[0][t + 192];
        sy = sh[1][t] + sh[1][t + 64] + sh[1][t + 128] + sh[1][t + 192];
        qx = sh[2][t] + sh[2][t + 64] + sh[2][t + 128] + sh[2][t + 192];
        qy = sh[3][t] + sh[3][t + 64] + sh[3][t + 128] + sh[3][t + 192];
        float* rep = stats + (blockIdx.x & (NREP - 1)) * 2 * Hh;   // spread RMW lines 8x
        atomicAdd(&rep[2 * t], sx);
        atomicAdd(&rep[2 * t + 1], sy);
        atomicAdd(&rep[Hh + 2 * t], qx);
        atomicAdd(&rep[Hh + 2 * t + 1], qy);
    }
}

// ---------------- MFMA GEMM, fused BN-normalize+ReLU on A (layers 1,2) ----------------
__global__ __launch_bounds__(256) void k_gemm(const u16* __restrict__ Xin,
                                              const u16* __restrict__ WT,
                                              u16* __restrict__ Yh,
                                              const float* __restrict__ stats,
                                              const float* __restrict__ gam,
                                              const float* __restrict__ bet) {
    __shared__ u16 wt[Hh * 136];
    __shared__ float s_scale[Hh], s_shift[Hh];
    int tid = threadIdx.x;

    if (tid < Hh) {
        float s0 = 0.f, s1 = 0.f;
#pragma unroll
        for (int r = 0; r < NREP; r++) {          // sum replica slabs
            s0 += stats[r * 2 * Hh + tid];
            s1 += stats[r * 2 * Hh + Hh + tid];
        }
        float mu = s0 * (1.0f / Nn);
        float var = s1 * (1.0f / Nn) - mu * mu;
        float sc = rsqrtf(var + EPSf) * gam[tid];
        s_scale[tid] = sc;
        s_shift[tid] = bet[tid] - mu * sc;
    }
#pragma unroll
    for (int i = 0; i < 8; i++) {
        int v = tid + 256 * i;            // uint4 idx over 2048
        int n = v >> 4, k8 = v & 15;
        uint4 d = ((const uint4*)WT)[v];
        *((uint4*)(wt + n * 136 + k8 * 8)) = d;
    }
    __syncthreads();

    int wv = tid >> 6, lane = tid & 63;
    int m = lane & 15, q = lane >> 4;
    int row0 = blockIdx.x * 64 + wv * 16;
    int lrow = row0 + m;
    if (lrow >= Nn) lrow = Nn - 1;        // clamp load row; stores guarded
    const u16* xrow = Xin + lrow * Hh + q * 8;

    f32x4 acc[8] = {};
#pragma unroll
    for (int k0 = 0; k0 < Hh; k0 += 32) {
        int cb = k0 + q * 8;
        uint4 p = *(const uint4*)(xrow + k0);
        float4 sc0 = *(const float4*)(s_scale + cb);
        float4 sc1 = *(const float4*)(s_scale + cb + 4);
        float4 sh0 = *(const float4*)(s_shift + cb);
        float4 sh1 = *(const float4*)(s_shift + cb + 4);
        float f0 = fmaxf(bf_lo(p.x) * sc0.x + sh0.x, 0.0f);
        float f1 = fmaxf(bf_hi(p.x) * sc0.y + sh0.y, 0.0f);
        float f2 = fmaxf(bf_lo(p.y) * sc0.z + sh0.z, 0.0f);
        float f3 = fmaxf(bf_hi(p.y) * sc0.w + sh0.w, 0.0f);
        float f4 = fmaxf(bf_lo(p.z) * sc1.x + sh1.x, 0.0f);
        float f5 = fmaxf(bf_hi(p.z) * sc1.y + sh1.y, 0.0f);
        float f6 = fmaxf(bf_lo(p.w) * sc1.z + sh1.z, 0.0f);
        float f7 = fmaxf(bf_hi(p.w) * sc1.w + sh1.w, 0.0f);
        union { bf16x8 v; u32 u[4]; } cv;
        cv.u[0] = pack2(f0, f1);
        cv.u[1] = pack2(f2, f3);
        cv.u[2] = pack2(f4, f5);
        cv.u[3] = pack2(f6, f7);
        bf16x8 a = cv.v;
#pragma unroll
        for (int t = 0; t < 8; t++) {
            bf16x8 b = *(const bf16x8*)(wt + (t * 16 + m) * 136 + k0 + q * 8);
            acc[t] = __builtin_amdgcn_mfma_f32_16x16x32_bf16(a, b, acc[t], 0, 0, 0);
        }
    }

    int orow0 = row0 + q * 4;
#pragma unroll
    for (int t = 0; t < 8; t++) {
#pragma unroll
        for (int r = 0; r < 4; r++) {
            int rr = orow0 + r;
            if (rr < Nn) Yh[rr * Hh + t * 16 + m] = f2bf(acc[t][r]);
        }
    }
}

// ---------------- fused BN + mean pool + MLP head: 256 thr, split-row pool + split-k MLP ----------------
__global__ __launch_bounds__(256) void k_poolmlp(const u16* __restrict__ Ah,
                                                 const float* __restrict__ stats,
                                                 const float* __restrict__ gam,
                                                 const float* __restrict__ bet,
                                                 const int* __restrict__ gstart,
                                                 const float* __restrict__ W1,
                                                 const float* __restrict__ b1,
                                                 const float* __restrict__ W2,
                                                 const float* __restrict__ b2,
                                                 float* __restrict__ out) {
    int g = blockIdx.x;
    int t = threadIdx.x;
    int c = t & 127, h = t >> 7;          // h: row/k half
    __shared__ float pp[2][Hh];
    __shared__ float p[Hh];
    __shared__ float hpart[2][Hh];
    __shared__ float hid[Hh];

    float s0 = 0.f, s1 = 0.f;
#pragma unroll
    for (int r = 0; r < NREP; r++) {
        s0 += stats[r * 2 * Hh + c];
        s1 += stats[r * 2 * Hh + Hh + c];
    }
    float mu = s0 * (1.0f / Nn);
    float var = s1 * (1.0f / Nn) - mu * mu;
    float sc = rsqrtf(var + EPSf) * gam[c];
    float sf = bet[c] - mu * sc;

    int s = gstart[g], e = gstart[g + 1];
    float sum = 0.0f;
    for (int r = s + h; r < e; r += 2) {  // two row-halves in parallel
        float v = __uint_as_float((u32)Ah[r * Hh + c] << 16);
        sum += fmaxf(v * sc + sf, 0.0f);
    }
    pp[h][c] = sum;
    __syncthreads();
    if (h == 0) {
        int n = e - s;
        p[c] = (pp[0][c] + pp[1][c]) / (float)(n > 1 ? n : 1);
    }
    __syncthreads();
    float acc = (h == 0) ? b1[c] : 0.0f;  // split-k over W1
    for (int k = h * 64; k < h * 64 + 64; k++) acc += p[k] * W1[k * Hh + c];
    hpart[h][c] = acc;
    __syncthreads();
    if (h == 0) hid[c] = fmaxf(hpart[0][c] + hpart[1][c], 0.0f);
    __syncthreads();
    if (t < Cc) {
        float acc2 = b2[t];
        for (int k = 0; k < Hh; k++) acc2 += hid[k] * W2[k * Cc + t];
        out[g * Cc + t] = acc2;
    }
}

extern "C" void kernel_launch(void* const* d_in, const int* in_sizes, int n_in,
                              void* d_out, int out_size, void* d_ws, size_t ws_size,
                              hipStream_t stream) {
    const float* x      = (const float*)d_in[0];
    const int*   ei     = (const int*)d_in[1];
    const int*   batch  = (const int*)d_in[2];
    const float* conv_w = (const float*)d_in[3];
    const float* conv_b = (const float*)d_in[4];
    const float* bn_g   = (const float*)d_in[5];
    const float* bn_b   = (const float*)d_in[6];
    const float* w1     = (const float*)d_in[7];
    const float* b1     = (const float*)d_in[8];
    const float* w2     = (const float*)d_in[9];
    const float* b2     = (const float*)d_in[10];
    float* out = (float*)d_out;

    u16*   Yh      = (u16*)d_ws;                  // N*H bf16 row-major (gemm out)
    u16*   Ah      = Yh + Nn * Hh;                // N*H bf16 row-major (gather out)
    u16*   WT      = Ah + Nn * Hh;                // 3*H*H bf16 (W^T)
    float* dis     = (float*)(WT + 3 * Hh * Hh);  // N
    float* stats3  = dis + Nn;                    // 3 * STS (replica slabs)
    int*   rs      = (int*)(stats3 + 3 * STS);    // N+1 local-exclusive starts
    int*   rs2     = rs + Nn + 1;                 // N+1 globalized starts
    int*   gstart  = rs2 + Nn + 1;                // G+1
    int*   bsum    = gstart + Gg + 1;             // NSB
    u32*   recs    = (u32*)(bsum + NSB);          // E packed 4B records
    u16*   rankL   = (u16*)(recs + Ee);           // E within-(block,node) ranks
    u32*   partials = (u32*)(rankL + Ee);         // NBH * NW packed partial hists
    u32*   base_off = partials + NBH * NW;        // NBH * NW packed excl. offsets

    // ---- prologue: W^T; {histogram || layer-0 GEMM}; CSR build ----
    k_pre<<<3, 256, 0, stream>>>(conv_w, WT, stats3);
    k_pro<<<NBH + GT4, 1024, 50000, stream>>>(ei + Ee, rankL, partials, x, WT, Yh);
    k_scan1<<<NSB, 256, 0, stream>>>(partials, base_off, rs, bsum, dis, batch, gstart);
    k_fill<<<(Ee + 255) / 256, 256, 0, stream>>>(ei, rs, bsum, rs2, rankL, base_off,
                                                 dis, recs);

    for (int l = 0; l < 3; l++) {
        k_gather<<<(Nn + 3) / 4, 256, 0, stream>>>(Yh, dis, conv_b + l * Hh, rs2,
                                                   recs, Ah);
        k_stats<<<256, 256, 0, stream>>>(Ah, stats3 + l * STS);
        if (l < 2) {
            k_gemm<<<(Nn + 63) / 64, 256, 0, stream>>>(Ah, WT + (l + 1) * Hh * Hh, Yh,
                                                       stats3 + l * STS,
                                                       bn_g + l * Hh, bn_b + l * Hh);
        }
    }

    k_poolmlp<<<Gg, 256, 0, stream>>>(Ah, stats3 + 2 * STS, bn_g + 2 * Hh,
                                      bn_b + 2 * Hh, gstart, w1, b1, w2, b2, out);
}